// Round 14
// baseline (199.701 us; speedup 1.0000x reference)
//
#include <hip/hip_runtime.h>
#include <hip/hip_bf16.h>
#include <math.h>

// Problem constants (fixed by setup_inputs)
constexpr int B_ = 2;
constexpr int T_ = 2048;
constexpr int C_ = 1024;
constexpr int H_ = 16;
constexpr int D_ = 64;       // head dim
constexpr int M_ = B_ * T_;  // 4096 rows
constexpr float SHIFT_ = 5.0f;
constexpr float P_MIN_ = 1e-4f;
constexpr float P_MAX_ = 1e3f;
constexpr float V_MIN_ = 1e-10f;
// Q is pre-scaled by log2e/8 in the GEMM epilogue; P = exp2(s) directly.
// Any uniform factor on P cancels exactly in mean = (P@V)/(P@1).
constexpr float QS_ = 0.125f * 1.4426950408889634f;

typedef __attribute__((ext_vector_type(8))) short s16x8;
typedef __attribute__((ext_vector_type(8))) _Float16 h16x8;
typedef __attribute__((ext_vector_type(4))) float f32x4;
typedef unsigned short ushort_t;

__device__ __forceinline__ float clamp_p(float pp) {
    float s = (pp >= 0.f) ? 1.f : -1.f;
    return s * fminf(fmaxf(fabsf(pp), P_MIN_), P_MAX_);
}

// fp32 <-> fp16 bits (RTNE)
__device__ __forceinline__ ushort_t f2h(float f) {
    _Float16 h = (_Float16)f;
    return __builtin_bit_cast(unsigned short, h);
}
__device__ __forceinline__ float h2f(ushort_t h) {
    return (float)__builtin_bit_cast(_Float16, h);
}

// 2^x via v_exp_f32
__device__ __forceinline__ float fast_exp2(float x) {
#if __has_builtin(__builtin_amdgcn_exp2f)
    return __builtin_amdgcn_exp2f(x);
#else
    return __expf(x * 0.6931471805599453f);
#endif
}

// async global->LDS, 16B per lane. LDS dest must be (wave-uniform base + lane*16).
__device__ __forceinline__ void gload_lds16(const void* g, void* l) {
    __builtin_amdgcn_global_load_lds(
        (const __attribute__((address_space(1))) unsigned int*)g,
        (__attribute__((address_space(3))) unsigned int*)l, 16, 0, 0);
}

// ---------------------------------------------------------------------------
// prep_w: fused input prep -- x -> fp16 (blocks 0..4095), w_attn transpose
// (4096..4863), w_proj transpose (4864..5119), minmax-atomic init (5120).
// ---------------------------------------------------------------------------
__device__ __forceinline__ void convT_body(const float* __restrict__ W,
                                           ushort_t* __restrict__ Wth,
                                           int N, int K, int bx, int by,
                                           int tid, float (*tile)[65]) {
    const int k0 = by * 64, n0 = bx * 64;
    const int tr = tid >> 4;
    const int tc4 = (tid & 15) * 4;
#pragma unroll
    for (int i = 0; i < 4; ++i) {
        float4 f = *(const float4*)&W[(size_t)(k0 + tr + i * 16) * N + n0 + tc4];
        tile[tr + i * 16][tc4 + 0] = f.x;
        tile[tr + i * 16][tc4 + 1] = f.y;
        tile[tr + i * 16][tc4 + 2] = f.z;
        tile[tr + i * 16][tc4 + 3] = f.w;
    }
    __syncthreads();
#pragma unroll
    for (int i = 0; i < 4; ++i) {
        int n = tr + i * 16;
        ushort4 h;
        h.x = f2h(tile[tc4 + 0][n]);
        h.y = f2h(tile[tc4 + 1][n]);
        h.z = f2h(tile[tc4 + 2][n]);
        h.w = f2h(tile[tc4 + 3][n]);
        *(ushort4*)&Wth[(size_t)(n0 + n) * K + k0 + tc4] = h;
    }
}

__global__ __launch_bounds__(256)
void prep_w(const float* __restrict__ x, const float* __restrict__ w_attn,
            const float* __restrict__ w_proj, ushort_t* __restrict__ xh,
            ushort_t* __restrict__ wth, ushort_t* __restrict__ wtp,
            unsigned* __restrict__ umax, unsigned* __restrict__ umin) {
    __shared__ float tile[64][65];
    const int blk = blockIdx.x;
    const int tid = threadIdx.x;
    if (blk < 4096) {
        int idx = blk * 256 + tid;
        float4 f = ((const float4*)x)[idx];
        ushort4 h;
        h.x = f2h(f.x); h.y = f2h(f.y); h.z = f2h(f.z); h.w = f2h(f.w);
        ((ushort4*)xh)[idx] = h;
    } else if (blk < 4096 + 768) {
        int sub = blk - 4096;                  // w_attn: N=3C (48 n-tiles), K=C (16)
        convT_body(w_attn, wth, 3 * C_, C_, sub % 48, sub / 48, tid, tile);
    } else if (blk < 4096 + 768 + 256) {
        int sub = blk - 4864;                  // w_proj: N=C (16), K=C (16)
        convT_body(w_proj, wtp, C_, C_, sub % 16, sub / 16, tid, tile);
    } else {
        // init |v+5| max/min atomic buffers (B*C = 2048 each; keys >= 0)
#pragma unroll
        for (int j = 0; j < 8; ++j) {
            umax[j * 256 + tid] = 0u;
            umin[j * 256 + tid] = 0xFFFFFFFFu;
        }
    }
}

// ---------------------------------------------------------------------------
// fp16x1 MFMA GEMM (swapped operands: M-row on l16, 4 consecutive N-cols on
// (quad,r) -> packed stores).
// MODE 0 (proj): fp32 float4 out.
// MODE 1 (qkv): Q cols -> qkvh fp16 pre-scaled by qscale; V cols -> qkvh
//   fp16 + per-column |v+SHIFT| max/min atomics (z = p*log|v+5| is monotone
//   in |v+5|, so the zmax pass folds into this epilogue); K cols -> kbf
//   DIRECTLY in the dense swizzled attn layout (R13 bug: head index was
//   computed from the within-BLOCK column; must be the within-PLANE column).
// ---------------------------------------------------------------------------
template <int MODE>
__global__ __launch_bounds__(256)
void gemm1(const ushort_t* __restrict__ Ah, const ushort_t* __restrict__ Bh,
           const float* __restrict__ bias, void* __restrict__ Cout,
           ushort_t* __restrict__ kbf, unsigned* __restrict__ umax,
           unsigned* __restrict__ umin, int M, int N, int K, float qscale) {
    __shared__ ushort_t Lds[2 * 2 * 128 * 32];   // [plane][sub][row][32]

    const int tid = threadIdx.x;
    const int w = tid >> 6;
    const int lane = tid & 63;
    const int l16 = lane & 15;
    const int quad = lane >> 4;
    const int row0 = blockIdx.y * 128, col0 = blockIdx.x * 128;
    const int wr = w >> 1, wc = w & 1;

    const ushort_t* gb[8];
    ushort_t* lb[8];
#pragma unroll
    for (int j = 0; j < 8; ++j) {
        int q = j * 4 + w;
        int plane = q >> 4;
        int cc = q & 15;
        int sub = cc & 1;
        int r = (cc >> 1) * 16 + (lane >> 2);
        const ushort_t* src = plane ? Bh : Ah;
        int tb = plane ? col0 : row0;
        gb[j] = src + (size_t)(tb + r) * K + sub * 32 + (lane & 3) * 8;
        lb[j] = &Lds[plane * 8192 + sub * 4096 + r * 32 + (lane & 3) * 8];
    }

    f32x4 acc[4][4] = {};

    for (int k0 = 0; k0 < K; k0 += 64) {
        __syncthreads();
#pragma unroll
        for (int j = 0; j < 8; ++j)
            gload_lds16(gb[j] + k0, lb[j]);
        __syncthreads();

#pragma unroll
        for (int kk = 0; kk < 2; ++kk) {
            h16x8 af[4], bf[4];
#pragma unroll
            for (int mi = 0; mi < 4; ++mi)
                af[mi] = *(const h16x8*)&Lds[kk * 4096 + (wr * 64 + mi * 16 + l16) * 32 + quad * 8];
#pragma unroll
            for (int ni = 0; ni < 4; ++ni)
                bf[ni] = *(const h16x8*)&Lds[8192 + kk * 4096 + (wc * 64 + ni * 16 + l16) * 32 + quad * 8];
#pragma unroll
            for (int mi = 0; mi < 4; ++mi)
#pragma unroll
                for (int ni = 0; ni < 4; ++ni)
                    acc[mi][ni] = __builtin_amdgcn_mfma_f32_16x16x32_f16(bf[ni], af[mi], acc[mi][ni], 0, 0, 0);
        }
    }

    if (MODE == 0) {
#pragma unroll
        for (int mi = 0; mi < 4; ++mi) {
            int row = row0 + wr * 64 + mi * 16 + l16;
#pragma unroll
            for (int ni = 0; ni < 4; ++ni) {
                int colb = col0 + wc * 64 + ni * 16 + quad * 4;
                float4 bs = *(const float4*)&bias[colb];
                float4 pk = make_float4(acc[mi][ni][0] + bs.x, acc[mi][ni][1] + bs.y,
                                        acc[mi][ni][2] + bs.z, acc[mi][ni][3] + bs.w);
                *(float4*)&((float*)Cout)[(size_t)row * N + colb] = pk;
            }
        }
    } else {
        const int plane = col0 >> 10;            // 0 Q, 1 K, 2 V (C=1024)
        if (plane == 1) {
            // K: direct dense swizzled kbf write (layout matches attn reads)
            const int b = row0 >> 11;
#pragma unroll
            for (int mi = 0; mi < 4; ++mi) {
                int row = row0 + wr * 64 + mi * 16 + l16;
                int t = row & (T_ - 1);
#pragma unroll
                for (int ni = 0; ni < 4; ++ni) {
                    // IN-PLANE column (R13 bug: was missing col0 - C_)
                    int cp = (col0 - C_) + wc * 64 + ni * 16 + quad * 4;
                    float4 bs = *(const float4*)&bias[C_ + cp];
                    ushort4 pk;
                    pk.x = f2h(acc[mi][ni][0] + bs.x);
                    pk.y = f2h(acc[mi][ni][1] + bs.y);
                    pk.z = f2h(acc[mi][ni][2] + bs.z);
                    pk.w = f2h(acc[mi][ni][3] + bs.w);
                    int hh = cp >> 6, d = cp & 63;
                    int g = d >> 3, off = d & 7;                  // off in {0,4}
                    size_t addr = ((size_t)((b << 4) + hh) * T_ + t) * 64
                                + ((g ^ (t & 7)) << 3) + off;
                    *(ushort4*)&kbf[addr] = pk;
                }
            }
        } else {
            const float osc = (plane == 0) ? qscale : 1.0f;
            float cmx[4][4], cmn[4][4];
            if (plane == 2) {
#pragma unroll
                for (int ni = 0; ni < 4; ++ni)
#pragma unroll
                    for (int r = 0; r < 4; ++r) { cmx[ni][r] = 0.f; cmn[ni][r] = 3.4e38f; }
            }
#pragma unroll
            for (int mi = 0; mi < 4; ++mi) {
                int row = row0 + wr * 64 + mi * 16 + l16;
#pragma unroll
                for (int ni = 0; ni < 4; ++ni) {
                    int colb = col0 + wc * 64 + ni * 16 + quad * 4;
                    float4 bs = *(const float4*)&bias[colb];
                    float v0 = acc[mi][ni][0] + bs.x;
                    float v1 = acc[mi][ni][1] + bs.y;
                    float v2 = acc[mi][ni][2] + bs.z;
                    float v3 = acc[mi][ni][3] + bs.w;
                    if (plane == 2) {
                        float a0 = fabsf(v0 + SHIFT_), a1 = fabsf(v1 + SHIFT_);
                        float a2 = fabsf(v2 + SHIFT_), a3 = fabsf(v3 + SHIFT_);
                        cmx[ni][0] = fmaxf(cmx[ni][0], a0); cmn[ni][0] = fminf(cmn[ni][0], a0);
                        cmx[ni][1] = fmaxf(cmx[ni][1], a1); cmn[ni][1] = fminf(cmn[ni][1], a1);
                        cmx[ni][2] = fmaxf(cmx[ni][2], a2); cmn[ni][2] = fminf(cmn[ni][2], a2);
                        cmx[ni][3] = fmaxf(cmx[ni][3], a3); cmn[ni][3] = fminf(cmn[ni][3], a3);
                    }
                    ushort4 pk;
                    pk.x = f2h(v0 * osc); pk.y = f2h(v1 * osc);
                    pk.z = f2h(v2 * osc); pk.w = f2h(v3 * osc);
                    *(ushort4*)&((ushort_t*)Cout)[(size_t)row * N + colb] = pk;
                }
            }
            if (plane == 2) {
                // reduce over the 16 l16 lanes (rows), then one atomic per col
#pragma unroll
                for (int ni = 0; ni < 4; ++ni)
#pragma unroll
                    for (int r = 0; r < 4; ++r) {
#pragma unroll
                        for (int s = 1; s < 16; s <<= 1) {
                            cmx[ni][r] = fmaxf(cmx[ni][r], __shfl_xor(cmx[ni][r], s));
                            cmn[ni][r] = fminf(cmn[ni][r], __shfl_xor(cmn[ni][r], s));
                        }
                    }
                if (l16 == 0) {
                    const int b = row0 >> 11;
#pragma unroll
                    for (int ni = 0; ni < 4; ++ni)
#pragma unroll
                        for (int r = 0; r < 4; ++r) {
                            int cv = (col0 - 2 * C_) + wc * 64 + ni * 16 + quad * 4 + r;
                            atomicMax(&umax[b * C_ + cv], __float_as_uint(cmx[ni][r]));
                            atomicMin(&umin[b * C_ + cv], __float_as_uint(cmn[ni][r]));
                        }
                }
            }
        }
    }
}

// ---------------------------------------------------------------------------
// prep_v: V-only prep per (b,h,t-tile). Prologue finalizes zmax from the
// gemm's |v+5| max/min atomics: zm = p>=0 ? p*log(max) : p*log(min).
// V: GeM transform, transpose via LDS with k-axis bit-permutation
// pi(t) = [b5][b3b2][b4][b1b0] (matches in-register P layout), swizzled.
// ---------------------------------------------------------------------------
__global__ __launch_bounds__(256)
void prep_v(const ushort_t* __restrict__ qkvh, const float* __restrict__ p_param,
            const unsigned* __restrict__ umax, const unsigned* __restrict__ umin,
            float* __restrict__ zmax, ushort_t* __restrict__ vtbf) {
    __shared__ ushort_t VtL[64 * 72];
    __shared__ float zm_l[64];

    const int blk = blockIdx.x;
    const int tt = blk & 31;
    const int bh = blk >> 5;
    const int b = bh >> 4;
    const int h = bh & 15;
    const int t0 = tt * 64;

    const int tl = threadIdx.x >> 2;
    const int c0 = (threadIdx.x & 3) * 16;
    const int g0 = c0 >> 3;
    // pi(t): bits [b5][b3b2][b4][b1b0]
    const int ptl = ((tl >> 5) & 1) * 32 + ((tl >> 2) & 3) * 8
                  + ((tl >> 4) & 1) * 4 + (tl & 3);

    // ---- zmax finalize for this head's 64 channels ----
    if (threadIdx.x < 64) {
        int c = h * D_ + threadIdx.x;
        float pm = clamp_p(p_param[c]);
        float mp = fmaxf(__uint_as_float(umax[b * C_ + c]), V_MIN_);
        float mn = fmaxf(__uint_as_float(umin[b * C_ + c]), V_MIN_);
        float zm = (pm >= 0.f) ? pm * __logf(mp) : pm * __logf(mn);
        zm_l[threadIdx.x] = zm;
        zmax[b * C_ + c] = zm;   // redundant across tt blocks; same value
    }
    __syncthreads();

    // ---- V: GeM transform, store at column pi(t) ----
    {
        const ushort_t* vsrc = qkvh + (size_t)(b * T_ + t0 + tl) * 3 * C_
                             + 2 * C_ + h * D_ + c0;
        ushort_t tv[16];
        *(s16x8*)&tv[0] = *(const s16x8*)&vsrc[0];
        *(s16x8*)&tv[8] = *(const s16x8*)&vsrc[8];
#pragma unroll
        for (int q = 0; q < 16; ++q) {
            int j = c0 + q;
            float p = clamp_p(p_param[h * D_ + j]);
            float v = h2f(tv[q]);
            float z = p * __logf(fmaxf(fabsf(v + SHIFT_), V_MIN_));
            float val = __expf(z - zm_l[j]);
            VtL[j * 72 + ptl] = f2h(val);
        }
    }
    __syncthreads();
    {
        const int d = tl;
        s16x8 r0 = *(const s16x8*)&VtL[d * 72 + c0];
        s16x8 r1 = *(const s16x8*)&VtL[d * 72 + c0 + 8];
        size_t vbase = ((size_t)bh * 32 + tt) * 4096 + (size_t)d * 64;
        *(s16x8*)&vtbf[vbase + ((g0)     ^ (d & 7)) * 8] = r0;
        *(s16x8*)&vtbf[vbase + ((g0 + 1) ^ (d & 7)) * 8] = r1;
    }
}

// ---------------------------------------------------------------------------
// Attention helpers. SWAPPED QK^T (S^T = mfma(K,Q): q on l16, k on
// (nt,quad,r)) keeps P in registers; PV also swapped (O^T = mfma(V, P):
// q on l16, d on (quad,r)).
// ---------------------------------------------------------------------------
__device__ __forceinline__ void load_frag(h16x8 kf[2][4], const ushort_t* tile,
                                          int l16, int sg0, int sg1) {
#pragma unroll
    for (int nt = 0; nt < 4; ++nt) {
        kf[0][nt] = *(const h16x8*)&tile[(nt * 16 + l16) * 64 + sg0];
        kf[1][nt] = *(const h16x8*)&tile[(nt * 16 + l16) * 64 + sg1];
    }
}

__device__ __forceinline__ void tile_body2(const h16x8 qf[2][2], const h16x8 kf[2][4],
        const h16x8 vf[2][4], const h16x8 ones, bool diag, int l16, int quad, int qh,
        f32x4 O[2][4], f32x4 Ol[2]) {
#pragma unroll
    for (int m = 0; m < 2; ++m) {
        // ---- S^T = K Q^T : s[nt][r] = S[k=nt*16+quad*4+r][q=l16] ----
        f32x4 s[4] = {};
#pragma unroll
        for (int nt = 0; nt < 4; ++nt) {
            s[nt] = __builtin_amdgcn_mfma_f32_16x16x32_f16(kf[0][nt], qf[m][0], s[nt], 0, 0, 0);
            s[nt] = __builtin_amdgcn_mfma_f32_16x16x32_f16(kf[1][nt], qf[m][1], s[nt], 0, 0, 0);
        }

        // ---- causal mask (diag tile only): k on (nt,quad,r), q on l16 ----
        if (diag) {
            int row = qh * 32 + m * 16 + l16;            // q (tile-local)
#pragma unroll
            for (int nt = 0; nt < 4; ++nt)
#pragma unroll
                for (int r = 0; r < 4; ++r) {
                    int col = nt * 16 + quad * 4 + r;    // k (tile-local)
                    if (col > row) s[nt][r] = -3.0e38f;
                }
        }

        // ---- P = exp2(s), pack in-register into PV A-frags ----
#pragma unroll
        for (int ks = 0; ks < 2; ++ks) {
            ushort_t t8[8];
#pragma unroll
            for (int r = 0; r < 4; ++r) {
                t8[r]     = f2h(fast_exp2(s[2 * ks][r]));
                t8[4 + r] = f2h(fast_exp2(s[2 * ks + 1][r]));
            }
            h16x8 pa = *(const h16x8*)t8;
            // l row-sum, transposed: D[*][l16=q]
            Ol[m] = __builtin_amdgcn_mfma_f32_16x16x32_f16(ones, pa, Ol[m], 0, 0, 0);
            // O^T: D[(quad,r)=d][l16=q]
#pragma unroll
            for (int nt = 0; nt < 4; ++nt)
                O[m][nt] = __builtin_amdgcn_mfma_f32_16x16x32_f16(vf[ks][nt], pa, O[m][nt], 0, 0, 0);
        }
    }
}

// ---------------------------------------------------------------------------
// Flash attention + fused combine (unchanged from R12: K cross-tile dbuf,
// V single-buffered within-tile, LDS-staged full-line y stores).
// ---------------------------------------------------------------------------
__global__ __launch_bounds__(256, 2)
void attn_mfma(const ushort_t* __restrict__ qkvh,
               const ushort_t* __restrict__ kbf, const ushort_t* __restrict__ vtbf,
               const float* __restrict__ zmax, const float* __restrict__ p_param,
               ushort_t* __restrict__ yh) {
    __shared__ float Osum[2][64][33];
    __shared__ float Lsum[2][32];
    __shared__ float zm_l[64], ip_l[64];
    __shared__ ushort_t Ytile[64][72];

    const int tid = threadIdx.x;
    const int w = tid >> 6;
    const int lane = tid & 63;
    const int l16 = lane & 15;
    const int quad = lane >> 4;
    const int qh = w >> 1;        // q-half: local rows qh*32..+32
    const int kp = w & 1;         // k-tile parity

    const int qt = 31 - (blockIdx.x >> 5);   // heavy first
    const int bh = blockIdx.x & 31;
    const int b = bh >> 4;
    const int h = bh & 15;
    const int q0 = qt * 64;

    if (tid < 64) {
        int c = h * D_ + tid;
        zm_l[tid] = zmax[b * C_ + c];
        ip_l[tid] = 1.f / clamp_p(p_param[c]);
    }

    const int sg0 = ((0 + quad) ^ (l16 & 7)) * 8;
    const int sg1 = ((4 + quad) ^ (l16 & 7)) * 8;

    f32x4 O[2][4] = {};
    f32x4 Ol[2] = {};

    h16x8 ones;
#pragma unroll
    for (int i = 0; i < 8; ++i) ones[i] = (_Float16)1.0f;

    // ---- Q B-frags: direct fp16 loads (pre-scaled by log2e/8 in GEMM) ----
    h16x8 qf[2][2];
#pragma unroll
    for (int m = 0; m < 2; ++m) {
        const int qrow = q0 + qh * 32 + m * 16 + l16;
        const ushort_t* qrp = qkvh + (size_t)(b * T_ + qrow) * 3 * C_ + h * D_;
#pragma unroll
        for (int ks = 0; ks < 2; ++ks)
            qf[m][ks] = *(const h16x8*)&qrp[ks * 32 + quad * 8];
    }

    const ushort_t* khead = kbf + (size_t)bh * T_ * 64;
    const ushort_t* vhead = vtbf + (size_t)bh * 32 * 4096;

    if (kp <= qt) {
        h16x8 kfA[2][4], kfB[2][4], vf[2][4];
        load_frag(kfA, khead + (size_t)kp * 4096, l16, sg0, sg1);

        for (int kt = kp; kt <= qt; kt += 4) {
            load_frag(vf, vhead + (size_t)kt * 4096, l16, sg0, sg1);
            int ktB = (kt + 2 <= qt) ? kt + 2 : kt;   // dummy reload on tail
            load_frag(kfB, khead + (size_t)ktB * 4096, l16, sg0, sg1);
            tile_body2(qf, kfA, vf, ones, kt == qt, l16, quad, qh, O, Ol);
            if (kt + 2 > qt) break;
            load_frag(vf, vhead + (size_t)(kt + 2) * 4096, l16, sg0, sg1);
            int ktA = (kt + 4 <= qt) ? kt + 4 : kt + 2;
            load_frag(kfA, khead + (size_t)ktA * 4096, l16, sg0, sg1);
            tile_body2(qf, kfB, vf, ones, kt + 2 == qt, l16, quad, qh, O, Ol);
        }
    }

    // ---- merge k-parity partials: kp0 publishes; kp1 merges + transform ----
    if (kp == 0) {
#pragma unroll
        for (int m = 0; m < 2; ++m) {
#pragma unroll
            for (int nt = 0; nt < 4; ++nt)
#pragma unroll
                for (int r = 0; r < 4; ++r)
                    Osum[qh][nt * 16 + quad * 4 + r][m * 16 + l16] = O[m][nt][r];
            if (quad == 0) Lsum[qh][m * 16 + l16] = Ol[m][0];
        }
    }
    __syncthreads();
    if (kp == 1) {
#pragma unroll
        for (int m = 0; m < 2; ++m) {
            int ql = m * 16 + l16;                       // local q (0..31)
            float inv_den = 1.f / (Ol[m][0] + Lsum[qh][ql]);
#pragma unroll
            for (int nt = 0; nt < 4; ++nt) {
                ushort4 pk;
#pragma unroll
                for (int r = 0; r < 4; ++r) {
                    int d = nt * 16 + quad * 4 + r;
                    float mean = (O[m][nt][r] + Osum[qh][d][ql]) * inv_den;
                    float y = __expf((zm_l[d] + __logf(mean)) * ip_l[d]) - SHIFT_;
                    ((ushort_t*)&pk)[r] = f2h(y);
                }
                *(ushort4*)&Ytile[qh * 32 + ql][nt * 16 + quad * 4] = pk;
            }
        }
    }
    __syncthreads();

    // ---- cooperative full-line store: 64 rows x 128B, all 4 waves ----
#pragma unroll
    for (int it = 0; it < 2; ++it) {
        int c = it * 256 + tid;
        int row = c >> 3;
        int part = c & 7;
        s16x8 v = *(const s16x8*)&Ytile[row][part * 8];
        *(s16x8*)&yh[(size_t)(b * T_ + q0 + row) * C_ + h * D_ + part * 8] = v;
    }
}

// ---------------------------------------------------------------------------
extern "C" void kernel_launch(void* const* d_in, const int* in_sizes, int n_in,
                              void* d_out, int out_size, void* d_ws, size_t ws_size,
                              hipStream_t stream) {
    const float* x      = (const float*)d_in[0];
    const float* w_attn = (const float*)d_in[1];
    const float* b_attn = (const float*)d_in[2];
    const float* w_proj = (const float*)d_in[3];
    const float* b_proj = (const float*)d_in[4];
    const float* p_par  = (const float*)d_in[5];
    float* out = (float*)d_out;

    char* ws = (char*)d_ws;
    ushort_t* qkvh = (ushort_t*)ws;                           // M x 3C fp16 (K-plane unused)
    ushort_t* xh   = qkvh + (size_t)M_ * 3 * C_;              // M x C fp16 (aliases yh)
    ushort_t* wth  = xh + (size_t)M_ * C_;                    // 3C x C fp16
    ushort_t* wtp  = wth + (size_t)3 * C_ * C_;               // C x C fp16
    float* zmax = (float*)(wtp + (size_t)C_ * C_);            // B x C
    ushort_t* kbf  = (ushort_t*)(zmax + B_ * C_);             // BH x T x 64 fp16
    ushort_t* vtbf = kbf + (size_t)B_ * H_ * T_ * 64;         // BH x 32 x 64 x 64 fp16
    unsigned* umax = (unsigned*)(vtbf + (size_t)B_ * H_ * T_ * 64);  // B x C
    unsigned* umin = umax + B_ * C_;                                  // B x C

    // 1) fused: x -> fp16, w transposes, atomic-minmax init
    prep_w<<<4096 + 768 + 256 + 1, 256, 0, stream>>>(x, w_attn, w_proj,
                                                     xh, wth, wtp, umax, umin);
    // 2) qkv GEMM: Q (scaled) + V -> qkvh fp16; K -> kbf swizzled;
    //    V |v+5| max/min atomics (zmax folded in)
    gemm1<1><<<dim3(3 * C_ / 128, M_ / 128), 256, 0, stream>>>(
        xh, wth, b_attn, qkvh, kbf, umax, umin, M_, 3 * C_, C_, QS_);
    // 3) prep V (zmax finalize in prologue; GeM transform, transpose+pi)
    prep_v<<<B_ * H_ * 32, 256, 0, stream>>>(qkvh, p_par, umax, umin, zmax, vtbf);
    // 4) MFMA flash attention + fused combine -> yh (alias xh)
    attn_mfma<<<B_ * H_ * (T_ / 64), 256, 0, stream>>>(qkvh, kbf, vtbf,
                                                       zmax, p_par, xh);
    // 5) out = y @ w_proj + b_proj (fp32 out)
    gemm1<0><<<dim3(C_ / 128, M_ / 128), 256, 0, stream>>>(
        xh, wtp, b_proj, out, nullptr, nullptr, nullptr, M_, C_, C_, 1.0f);
}